// Round 18
// baseline (710.739 us; speedup 1.0000x reference)
//
#include <hip/hip_runtime.h>
#include <hip/hip_cooperative_groups.h>
#include <hip/hip_bf16.h>
#include <math.h>

namespace cg = cooperative_groups;

// ---------------------------------------------------------------------------
// DualHeadGAT R18: cooperative persistent megakernel. All stages of R16
// (best, 226.9us) as grid-stride phases with grid.sync() between — removes
// ~7 inter-dispatch gaps (~8us each measured in R13). Phase bodies are the
// proven R16/R12 kernels; gemm1 uses the R15 half-wave form (lower VGPR).
// Grid sized via occupancy API (cooperative co-residency safe).
// N=50000, IN=128, E=800000. f32 in/out, int32 edges. 1 dispatch.
// ---------------------------------------------------------------------------

#define LRELU_SLOPE 0.2f

typedef __attribute__((ext_vector_type(8))) short short8;   // 8 bf16 = 4 VGPR
typedef __attribute__((ext_vector_type(4))) float f32x4;

__device__ inline ushort f2bf(float f) {            // RNE f32 -> bf16
    uint u = __float_as_uint(f);
    return (ushort)((u + 0x7FFFu + ((u >> 16) & 1u)) >> 16);
}
__device__ inline float bf2f(ushort u) {
    return __uint_as_float(((uint)u) << 16);
}

// ------- pre-fragment W[K][16J] (f32, row-major) into MFMA B-frag order ----
__device__ inline void prefrag_one(const float* __restrict__ W,
                                   ushort* __restrict__ out,
                                   int tid, int T, int ldn)
{
    int l = tid & 63, jt = tid >> 6;
    int t = jt % T, j = jt / T;
    int n = j * 16 + (l & 15);
    int k0 = t * 32 + (l >> 4) * 8;
    ushort o[8];
    #pragma unroll
    for (int b = 0; b < 8; ++b) o[b] = f2bf(W[(size_t)(k0 + b) * ldn + n]);
    *(short8*)(out + (size_t)tid * 8) = *(short8*)o;
}

// ---- gemm1 half-wave body (R15, correctness-proven): K=128 -> 256 cols ----
__device__ inline void gemm1_half(int wv, const ushort* __restrict__ A,
                                  const ushort* __restrict__ Bf,
                                  ushort* __restrict__ Cbf,
                                  const float* __restrict__ attS,
                                  const float* __restrict__ attD,
                                  float* __restrict__ as_,
                                  float* __restrict__ ad_, int M)
{
    const int rowTile = wv >> 1;
    const int half = wv & 1;             // column half (heads 0-1 / 2-3)
    const int base = rowTile * 16;
    if (base >= M) return;
    const int l = threadIdx.x & 63;
    const int lm = l & 15, lg = l >> 4;

    short8 a[4];
    const ushort* ap = A + (size_t)(base + lm) * 128 + lg * 8;
    #pragma unroll
    for (int t = 0; t < 4; ++t) a[t] = *(const short8*)(ap + t * 32);

    f32x4 acc[8];
    #pragma unroll
    for (int j = 0; j < 8; ++j) acc[j] = (f32x4){0.f, 0.f, 0.f, 0.f};

    const ushort* bp = Bf + (size_t)l * 8;
    #pragma unroll
    for (int j = 0; j < 8; ++j) {
        const int jg = half * 8 + j;
        #pragma unroll
        for (int t = 0; t < 4; ++t) {
            short8 b = *(const short8*)(bp + (size_t)(jg * 4 + t) * 512);
            acc[j] = __builtin_amdgcn_mfma_f32_16x16x32_bf16(a[t], b, acc[j], 0, 0, 0);
        }
    }

    float sp[2][4], dp[2][4];
    #pragma unroll
    for (int h = 0; h < 2; ++h)
        #pragma unroll
        for (int r = 0; r < 4; ++r) { sp[h][r] = 0.f; dp[h][r] = 0.f; }

    #pragma unroll
    for (int j = 0; j < 8; ++j) {
        const int h = j >> 2;
        const int hg = half * 2 + h;
        float ws = attS[hg * 64 + (j & 3) * 16 + lm];
        float wd = attD[hg * 64 + (j & 3) * 16 + lm];
        #pragma unroll
        for (int r = 0; r < 4; ++r) {
            int row = base + lg * 4 + r;
            Cbf[(size_t)row * 256 + (half * 8 + j) * 16 + lm] = f2bf(acc[j][r]);
            sp[h][r] = fmaf(acc[j][r], ws, sp[h][r]);
            dp[h][r] = fmaf(acc[j][r], wd, dp[h][r]);
        }
    }
    #pragma unroll
    for (int h = 0; h < 2; ++h)
        #pragma unroll
        for (int r = 0; r < 4; ++r) {
            float s = sp[h][r], d = dp[h][r];
            s += __shfl_xor(s, 1); d += __shfl_xor(d, 1);
            s += __shfl_xor(s, 2); d += __shfl_xor(d, 2);
            s += __shfl_xor(s, 4); d += __shfl_xor(d, 4);
            s += __shfl_xor(s, 8); d += __shfl_xor(d, 8);
            if (lm == 0) {
                int row = base + lg * 4 + r;
                as_[row * 4 + half * 2 + h] = s;
                ad_[row * 4 + half * 2 + h] = d;
            }
        }
}

// ---- gemm2 wave body (R12 form): K=256 -> 64 cols, fused att2 dots --------
__device__ inline void gemm2_wave(int wid, const ushort* __restrict__ A,
                                  const ushort* __restrict__ Bf,
                                  ushort* __restrict__ Cbf,
                                  const float* __restrict__ attS,
                                  const float* __restrict__ attD,
                                  float* __restrict__ as_,
                                  float* __restrict__ ad_, int M)
{
    constexpr int J = 4, T = 8;
    const int l = threadIdx.x & 63;
    const int base = wid * 16;
    if (base >= M) return;
    const int lm = l & 15, lg = l >> 4;

    short8 a[T];
    const ushort* ap = A + (size_t)(base + lm) * 256 + lg * 8;
    #pragma unroll
    for (int t = 0; t < T; ++t) a[t] = *(const short8*)(ap + t * 32);

    f32x4 acc[J];
    #pragma unroll
    for (int j = 0; j < J; ++j) acc[j] = (f32x4){0.f, 0.f, 0.f, 0.f};

    const ushort* bp = Bf + (size_t)l * 8;
    #pragma unroll
    for (int j = 0; j < J; ++j)
        #pragma unroll
        for (int t = 0; t < T; ++t) {
            short8 b = *(const short8*)(bp + (size_t)(j * T + t) * 512);
            acc[j] = __builtin_amdgcn_mfma_f32_16x16x32_bf16(a[t], b, acc[j], 0, 0, 0);
        }

    float sp[4], dp[4];
    #pragma unroll
    for (int r = 0; r < 4; ++r) { sp[r] = 0.f; dp[r] = 0.f; }

    #pragma unroll
    for (int j = 0; j < J; ++j) {
        const int coff = j * 16 + lm;
        float ws = attS[coff];
        float wd = attD[coff];
        #pragma unroll
        for (int r = 0; r < 4; ++r) {
            int row = base + lg * 4 + r;
            Cbf[(size_t)row * 64 + j * 16 + lm] = f2bf(acc[j][r]);
            sp[r] = fmaf(acc[j][r], ws, sp[r]);
            dp[r] = fmaf(acc[j][r], wd, dp[r]);
        }
    }
    #pragma unroll
    for (int r = 0; r < 4; ++r) {
        float s = sp[r], d = dp[r];
        s += __shfl_xor(s, 1); d += __shfl_xor(d, 1);
        s += __shfl_xor(s, 2); d += __shfl_xor(d, 2);
        s += __shfl_xor(s, 4); d += __shfl_xor(d, 4);
        s += __shfl_xor(s, 8); d += __shfl_xor(d, 8);
        if (lm == 0) {
            int row = base + lg * 4 + r;
            as_[row] = s;
            ad_[row] = d;
        }
    }
}

// ---- agg1 wave body (R12 form, proven at the 67us gather floor) -----------
__device__ inline void agg1_wave(int w, const int* __restrict__ rowptr,
                                 const int* __restrict__ csr_src,
                                 const ushort* __restrict__ h1,
                                 const float* __restrict__ as_,
                                 const float* __restrict__ ad_,
                                 const float* __restrict__ bias,
                                 ushort* __restrict__ outbf)
{
    const int lane = threadIdx.x & 63;
    const int head = lane >> 4;
    const int c0 = lane << 2;
    const int my = lane & 3;
    const int hb = lane & 48;
    const float ad = ad_[w * 4 + head];
    float4 acc;
    float dsum;

    {   // implicit self-loop
        float el = as_[w * 4 + head] + ad;
        el = el > 0.f ? el : LRELU_SLOPE * el;
        float p = __expf(el);
        ushort4 u = *(const ushort4*)(h1 + (size_t)w * 256 + c0);
        acc.x = p * bf2f(u.x); acc.y = p * bf2f(u.y);
        acc.z = p * bf2f(u.z); acc.w = p * bf2f(u.w);
        dsum = p;
    }

    int e = rowptr[w];
    const int e1 = rowptr[w + 1];
    for (; e + 3 < e1; e += 4) {
        int s0 = csr_src[e],     s1 = csr_src[e + 1];
        int s2 = csr_src[e + 2], s3 = csr_src[e + 3];
        ushort4 u0 = *(const ushort4*)(h1 + (size_t)s0 * 256 + c0);
        ushort4 u1 = *(const ushort4*)(h1 + (size_t)s1 * 256 + c0);
        ushort4 u2 = *(const ushort4*)(h1 + (size_t)s2 * 256 + c0);
        ushort4 u3 = *(const ushort4*)(h1 + (size_t)s3 * 256 + c0);
        int ms = s0;
        ms = (my == 1) ? s1 : ms;
        ms = (my == 2) ? s2 : ms;
        ms = (my == 3) ? s3 : ms;
        float ev = as_[ms * 4 + head] + ad;
        ev = ev > 0.f ? ev : LRELU_SLOPE * ev;
        float pl = __expf(ev);
        float p0 = __shfl(pl, hb | 0);
        float p1 = __shfl(pl, hb | 1);
        float p2 = __shfl(pl, hb | 2);
        float p3 = __shfl(pl, hb | 3);
        acc.x = fmaf(p0, bf2f(u0.x), acc.x); acc.y = fmaf(p0, bf2f(u0.y), acc.y);
        acc.z = fmaf(p0, bf2f(u0.z), acc.z); acc.w = fmaf(p0, bf2f(u0.w), acc.w);
        acc.x = fmaf(p1, bf2f(u1.x), acc.x); acc.y = fmaf(p1, bf2f(u1.y), acc.y);
        acc.z = fmaf(p1, bf2f(u1.z), acc.z); acc.w = fmaf(p1, bf2f(u1.w), acc.w);
        acc.x = fmaf(p2, bf2f(u2.x), acc.x); acc.y = fmaf(p2, bf2f(u2.y), acc.y);
        acc.z = fmaf(p2, bf2f(u2.z), acc.z); acc.w = fmaf(p2, bf2f(u2.w), acc.w);
        acc.x = fmaf(p3, bf2f(u3.x), acc.x); acc.y = fmaf(p3, bf2f(u3.y), acc.y);
        acc.z = fmaf(p3, bf2f(u3.z), acc.z); acc.w = fmaf(p3, bf2f(u3.w), acc.w);
        dsum += (p0 + p1) + (p2 + p3);
    }
    for (; e < e1; ++e) {
        int s0 = csr_src[e];
        float e0 = as_[s0 * 4 + head] + ad;
        e0 = e0 > 0.f ? e0 : LRELU_SLOPE * e0;
        float p0 = __expf(e0);
        ushort4 u0 = *(const ushort4*)(h1 + (size_t)s0 * 256 + c0);
        acc.x = fmaf(p0, bf2f(u0.x), acc.x); acc.y = fmaf(p0, bf2f(u0.y), acc.y);
        acc.z = fmaf(p0, bf2f(u0.z), acc.z); acc.w = fmaf(p0, bf2f(u0.w), acc.w);
        dsum += p0;
    }
    const float inv = 1.f / (dsum + 1e-16f);
    const float4 b = *(const float4*)(bias + c0);
    float ox = acc.x * inv + b.x; ox = ox > 0.f ? ox : expm1f(ox);
    float oy = acc.y * inv + b.y; oy = oy > 0.f ? oy : expm1f(oy);
    float oz = acc.z * inv + b.z; oz = oz > 0.f ? oz : expm1f(oz);
    float ow = acc.w * inv + b.w; ow = ow > 0.f ? ow : expm1f(ow);
    ushort4 o;
    o.x = f2bf(ox); o.y = f2bf(oy); o.z = f2bf(oz); o.w = f2bf(ow);
    *(ushort4*)(outbf + (size_t)w * 256 + c0) = o;
}

// ---- agg2 wave body (R16 form) + scoring head -----------------------------
__device__ inline void agg2_wave(int w, const int* __restrict__ rowptr,
                                 const int* __restrict__ csr_src,
                                 const ushort* __restrict__ h2,
                                 const float* __restrict__ as_,
                                 const float* __restrict__ ad_,
                                 const float* __restrict__ b2,
                                 const float* __restrict__ Wsv,
                                 const float* __restrict__ bs,
                                 float* __restrict__ hout,
                                 float* __restrict__ scores)
{
    const int lane = threadIdx.x & 63;
    const int my = lane & 3;
    const float ad = ad_[w];
    float acc, dsum;
    {   // implicit self-loop
        float el = as_[w] + ad;
        el = el > 0.f ? el : LRELU_SLOPE * el;
        float p = __expf(el);
        acc = p * bf2f(h2[(size_t)w * 64 + lane]);
        dsum = p;
    }
    int e = rowptr[w];
    const int e1 = rowptr[w + 1];
    for (; e + 3 < e1; e += 4) {
        int s0 = csr_src[e],     s1 = csr_src[e + 1];
        int s2 = csr_src[e + 2], s3 = csr_src[e + 3];
        ushort f0 = h2[(size_t)s0 * 64 + lane];
        ushort f1 = h2[(size_t)s1 * 64 + lane];
        ushort f2 = h2[(size_t)s2 * 64 + lane];
        ushort f3 = h2[(size_t)s3 * 64 + lane];
        int ms = s0;
        ms = (my == 1) ? s1 : ms;
        ms = (my == 2) ? s2 : ms;
        ms = (my == 3) ? s3 : ms;
        float ev = as_[ms] + ad;
        ev = ev > 0.f ? ev : LRELU_SLOPE * ev;
        float pl = __expf(ev);
        float p0 = __shfl(pl, 0);
        float p1 = __shfl(pl, 1);
        float p2 = __shfl(pl, 2);
        float p3 = __shfl(pl, 3);
        acc = fmaf(p0, bf2f(f0), acc);
        acc = fmaf(p1, bf2f(f1), acc);
        acc = fmaf(p2, bf2f(f2), acc);
        acc = fmaf(p3, bf2f(f3), acc);
        dsum += (p0 + p1) + (p2 + p3);
    }
    for (; e < e1; ++e) {
        int s0 = csr_src[e];
        float e0 = as_[s0] + ad;
        e0 = e0 > 0.f ? e0 : LRELU_SLOPE * e0;
        float p0 = __expf(e0);
        acc = fmaf(p0, bf2f(h2[(size_t)s0 * 64 + lane]), acc);
        dsum += p0;
    }
    float v = acc / (dsum + 1e-16f) + b2[lane];
    v = v > 0.f ? v : expm1f(v);
    hout[(size_t)w * 64 + lane] = v;
    float sc = v * Wsv[lane];
    #pragma unroll
    for (int off = 32; off; off >>= 1) sc += __shfl_down(sc, off);
    if (lane == 0) scores[w] = sc + bs[0];
}

// ---------------------------- the megakernel -------------------------------
__global__ __launch_bounds__(256)
void mega(const float* __restrict__ x, const int* __restrict__ esrc,
          const int* __restrict__ edst,
          const float* __restrict__ W1, const float* __restrict__ aS1,
          const float* __restrict__ aD1, const float* __restrict__ b1,
          const float* __restrict__ W2, const float* __restrict__ aS2,
          const float* __restrict__ aD2, const float* __restrict__ b2,
          const float* __restrict__ Ws, const float* __restrict__ bs,
          ushort* __restrict__ xbf, ushort* __restrict__ bfr1,
          ushort* __restrict__ bfr2, ushort* __restrict__ h1bf,
          ushort* __restrict__ hl1bf, ushort* __restrict__ h2bf,
          float* __restrict__ as1, float* __restrict__ ad1,
          float* __restrict__ as2, float* __restrict__ ad2,
          int* __restrict__ deg, int* __restrict__ order,
          int* __restrict__ rowptr, int* __restrict__ csr_src,
          int* __restrict__ blockSums, int* __restrict__ blockOff,
          float* __restrict__ hout, float* __restrict__ scores,
          int N, int E)
{
    cg::grid_group grid = cg::this_grid();
    const int G = gridDim.x;
    const int tid = threadIdx.x;
    const int lane = tid & 63;
    const int gtid = blockIdx.x * 256 + tid;
    const int nthr = G * 256;
    const int N4 = N >> 2;

    // ---------------- P0: zero deg ----------------
    for (int i = gtid; i < N4; i += nthr)
        ((int4*)deg)[i] = make_int4(0, 0, 0, 0);
    grid.sync();

    // ---------------- P1: conv + prefrags + hist(order) ----------------
    {
        const int nconv4 = N * 32;           // N*128/4
        const int nfrag1 = 16 * 4 * 64;      // 4096
        const int nfrag2 = 4 * 8 * 64;       // 2048
        const int nhist  = (E + 3) >> 2;
        const int tot = nconv4 + nfrag1 + nfrag2 + nhist;
        for (int t0 = gtid; t0 < tot; t0 += nthr) {
            int t = t0;
            if (t < nconv4) {
                int i = t << 2;
                float4 v = *(const float4*)(x + i);
                ushort4 o;
                o.x = f2bf(v.x); o.y = f2bf(v.y); o.z = f2bf(v.z); o.w = f2bf(v.w);
                *(ushort4*)(xbf + i) = o;
                continue;
            }
            t -= nconv4;
            if (t < nfrag1) { prefrag_one(W1, bfr1, t, 4, 256); continue; }
            t -= nfrag1;
            if (t < nfrag2) { prefrag_one(W2, bfr2, t, 8, 64); continue; }
            t -= nfrag2;
            int i = t << 2;
            if (i + 3 < E) {
                int4 v = *(const int4*)(edst + i);
                int4 o;
                o.x = atomicAdd(&deg[v.x], 1);
                o.y = atomicAdd(&deg[v.y], 1);
                o.z = atomicAdd(&deg[v.z], 1);
                o.w = atomicAdd(&deg[v.w], 1);
                *(int4*)(order + i) = o;
            } else {
                for (; i < E; ++i) order[i] = atomicAdd(&deg[edst[i]], 1);
            }
        }
    }
    grid.sync();

    // ---------------- P2: grid-wide exclusive scan of deg -> rowptr -----
    const int C4 = (N4 + G - 1) / G;         // int4 chunk per block
    {   // P2a: per-block chunk sums (wave 0 only)
        int c0 = blockIdx.x * C4;
        int c1 = c0 + C4; if (c1 > N4) c1 = N4;
        if (tid < 64) {
            int s = 0;
            for (int i = c0 + lane; i < c1; i += 64) {
                int4 v = ((const int4*)deg)[i];
                s += (v.x + v.y) + (v.z + v.w);
            }
            #pragma unroll
            for (int off = 32; off; off >>= 1) s += __shfl_down(s, off);
            if (lane == 0) blockSums[blockIdx.x] = s;
        }
    }
    grid.sync();
    {   // P2b: block 0 scans blockSums -> blockOff (exclusive), rowptr[N]
        if (blockIdx.x == 0) {
            __shared__ int ws4[4];
            const int seg = (G + 255) >> 8;
            int base = tid * seg;
            int s = 0;
            for (int k = 0; k < seg; ++k) {
                int i = base + k;
                if (i < G) s += blockSums[i];
            }
            int sc = s;
            #pragma unroll
            for (int off = 1; off < 64; off <<= 1) {
                int t2 = __shfl_up(sc, off);
                if (lane >= off) sc += t2;
            }
            int wv = tid >> 6;
            if (lane == 63) ws4[wv] = sc;
            __syncthreads();
            int wbase = 0;
            for (int k = 0; k < wv; ++k) wbase += ws4[k];
            int run = wbase + sc - s;
            for (int k = 0; k < seg; ++k) {
                int i = base + k;
                if (i < G) { blockOff[i] = run; run += blockSums[i]; }
            }
            if (tid == 255) rowptr[N] = run;
        }
    }
    grid.sync();
    {   // P2c: per-block chunk scan -> rowptr (wave 0 only)
        int c0 = blockIdx.x * C4;
        int c1 = c0 + C4; if (c1 > N4) c1 = N4;
        if (tid < 64 && c0 < c1) {
            int run0 = blockOff[blockIdx.x];
            for (int base = c0; base < c1; base += 64) {
                int i = base + lane;
                int4 v = (i < c1) ? ((const int4*)deg)[i] : make_int4(0, 0, 0, 0);
                int tsum = (v.x + v.y) + (v.z + v.w);
                int sc = tsum;
                #pragma unroll
                for (int off = 1; off < 64; off <<= 1) {
                    int t2 = __shfl_up(sc, off);
                    if (lane >= off) sc += t2;
                }
                if (i < c1) {
                    int excl = run0 + sc - tsum;
                    int4 o;
                    o.x = excl; o.y = excl + v.x; o.z = o.y + v.y; o.w = o.z + v.z;
                    ((int4*)rowptr)[i] = o;
                }
                run0 += __shfl(sc, 63);
            }
        }
    }
    grid.sync();

    // ---------------- P3: gemm1 (half-waves) + atomic-free scatter ------
    {
        const int gemmWaves = (N / 16) * 2;              // 6250
        const int gemmB = (gemmWaves + 3) / 4;           // 1563
        const int scatB = (E + 255) / 256;               // 3125
        const int totB = gemmB + scatB;
        for (int vb = blockIdx.x; vb < totB; vb += G) {
            if (vb < gemmB) {
                int wv = vb * 4 + (tid >> 6);
                if (wv < gemmWaves)
                    gemm1_half(wv, xbf, bfr1, h1bf, aS1, aD1, as1, ad1, N);
            } else {
                int i = (vb - gemmB) * 256 + tid;
                if (i < E)
                    csr_src[rowptr[edst[i]] + order[i]] = esrc[i];
            }
        }
    }
    grid.sync();

    // ---------------- P4: agg1 ----------------
    {
        const int stride = G * 4;
        for (int w = blockIdx.x * 4 + (tid >> 6); w < N; w += stride)
            agg1_wave(w, rowptr, csr_src, h1bf, as1, ad1, b1, hl1bf);
    }
    grid.sync();

    // ---------------- P5: gemm2 ----------------
    {
        const int tiles = N / 16;                        // 3125
        const int stride = G * 4;
        for (int wid = blockIdx.x * 4 + (tid >> 6); wid < tiles; wid += stride)
            gemm2_wave(wid, hl1bf, bfr2, h2bf, aS2, aD2, as2, ad2, N);
    }
    grid.sync();

    // ---------------- P6: agg2 + scoring head ----------------
    {
        const int stride = G * 4;
        for (int w = blockIdx.x * 4 + (tid >> 6); w < N; w += stride)
            agg2_wave(w, rowptr, csr_src, h2bf, as2, ad2, b2, Ws, bs,
                      hout, scores);
    }
}

// ---------------------------------------------------------------------------
extern "C" void kernel_launch(void* const* d_in, const int* in_sizes, int n_in,
                              void* d_out, int out_size, void* d_ws, size_t ws_size,
                              hipStream_t stream)
{
    const float* x    = (const float*)d_in[0];
    const int*   ei   = (const int*)d_in[1];
    const float* W1   = (const float*)d_in[2];
    const float* as1w = (const float*)d_in[3];
    const float* ad1w = (const float*)d_in[4];
    const float* b1   = (const float*)d_in[5];
    const float* W2   = (const float*)d_in[6];
    const float* as2w = (const float*)d_in[7];
    const float* ad2w = (const float*)d_in[8];
    const float* b2   = (const float*)d_in[9];
    const float* Ws   = (const float*)d_in[10];
    const float* bs   = (const float*)d_in[11];

    const int N  = in_sizes[0] / 128;   // 50000
    const int E  = in_sizes[1] / 2;     // 800000
    const int* esrc = ei;
    const int* edst = ei + E;

    // ---- workspace layout (16B-aligned chunks) ----
    ushort* h1bf  = (ushort*)d_ws;                       // N*256 bf16
    ushort* hl1bf = h1bf + (size_t)N * 256;              // N*256 bf16
    ushort* h2bf  = hl1bf + (size_t)N * 256;             // N*64 bf16
    ushort* xbf   = h2bf + (size_t)N * 64;               // N*128 bf16
    ushort* bfr1  = xbf + (size_t)N * 128;               // 32768
    ushort* bfr2  = bfr1 + 32768;                        // 16384
    float*  as1   = (float*)(bfr2 + 16384);              // N*4
    float*  ad1   = as1 + (size_t)N * 4;                 // N*4
    float*  as2   = ad1 + (size_t)N * 4;                 // N
    float*  ad2   = as2 + N;                             // N
    int*    deg    = (int*)(ad2 + N);                    // N
    int*    order  = deg + N;                            // E
    int*    rowptr = order + E;                          // N+1 (+pad)
    int*    csr_src= rowptr + N + 4;                     // E
    int*    blockSums = csr_src + E;                     // 4096
    int*    blockOff  = blockSums + 4096;                // 4096

    float* hout   = (float*)d_out;                       // N*64
    float* scores = hout + (size_t)N * 64;               // N

    // ---- cooperative grid sizing (co-residency safe) ----
    int dev = 0;
    hipGetDevice(&dev);
    int numCU = 256;
    hipDeviceGetAttribute(&numCU, hipDeviceAttributeMultiprocessorCount, dev);
    int occ = 0;
    hipOccupancyMaxActiveBlocksPerMultiprocessor(&occ, (const void*)mega, 256, 0);
    if (occ < 1) occ = 1;
    int G = numCU * occ;
    if (G > 2048) G = 2048;
    if (G < 64)   G = 64;

    void* args[] = {
        (void*)&x, (void*)&esrc, (void*)&edst,
        (void*)&W1, (void*)&as1w, (void*)&ad1w, (void*)&b1,
        (void*)&W2, (void*)&as2w, (void*)&ad2w, (void*)&b2,
        (void*)&Ws, (void*)&bs,
        (void*)&xbf, (void*)&bfr1, (void*)&bfr2,
        (void*)&h1bf, (void*)&hl1bf, (void*)&h2bf,
        (void*)&as1, (void*)&ad1, (void*)&as2, (void*)&ad2,
        (void*)&deg, (void*)&order, (void*)&rowptr, (void*)&csr_src,
        (void*)&blockSums, (void*)&blockOff,
        (void*)&hout, (void*)&scores,
        (void*)&N, (void*)&E
    };
    hipLaunchCooperativeKernel((const void*)mega, dim3(G), dim3(256),
                               args, 0, stream);
}

// Round 19
// 226.455 us; speedup vs baseline: 3.1385x; 3.1385x over previous
//
#include <hip/hip_runtime.h>
#include <hip/hip_bf16.h>
#include <math.h>

// ---------------------------------------------------------------------------
// DualHeadGAT R19 = R16 restored (proven best: 226.9 us).
//  - atomic-free scatter: K1's histogram captures atomicAdd return as
//    order[i]; K3 scatter is pure streaming csr_src[rowptr[d]+order[i]]=s.
//  - K3 co-launches gemm1 (MFMA) with the scatter (independent work).
//  - agg1: R12 form (4x unroll, shfl p-dedup) at its measured ~67us
//    gather-delivery floor (~6.5 TB/s blended L2/L3/HBM).
//  - deferred softmax normalization (exact; shift-invariance + bounded e).
// Rejected by experiment: p-precompute passes (R6/R8), multi-slot gathers
// (R7/R17), 8x unroll (R10), gemm2 fusion (R14), K3 occupancy fixes
// (R14/R15), cooperative megakernel (R18: VGPR-max across phases kills
// agg1 occupancy 66%->24%).
// N=50000, IN=128, E=800000. f32 in/out, int32 edges. 7 dispatches.
// ---------------------------------------------------------------------------

#define LRELU_SLOPE 0.2f

typedef __attribute__((ext_vector_type(8))) short short8;   // 8 bf16 = 4 VGPR
typedef __attribute__((ext_vector_type(4))) float f32x4;

__device__ inline ushort f2bf(float f) {            // RNE f32 -> bf16
    uint u = __float_as_uint(f);
    return (ushort)((u + 0x7FFFu + ((u >> 16) & 1u)) >> 16);
}
__device__ inline float bf2f(ushort u) {
    return __uint_as_float(((uint)u) << 16);
}

// ------- pre-fragment W[K][16J] (f32, row-major) into MFMA B-frag order ----
__device__ inline void prefrag_one(const float* __restrict__ W,
                                   ushort* __restrict__ out,
                                   int tid, int T, int ldn)
{
    int l = tid & 63, jt = tid >> 6;
    int t = jt % T, j = jt / T;
    int n = j * 16 + (l & 15);
    int k0 = t * 32 + (l >> 4) * 8;
    ushort o[8];
    #pragma unroll
    for (int b = 0; b < 8; ++b) o[b] = f2bf(W[(size_t)(k0 + b) * ldn + n]);
    *(short8*)(out + (size_t)tid * 8) = *(short8*)o;
}

// ---- K1: degree hist (captures order) + x conversion + weight prefrags ----
__global__ __launch_bounds__(256)
void fused_front(const float* __restrict__ x, ushort* __restrict__ xbf,
                 const float* __restrict__ W1, const float* __restrict__ W2,
                 ushort* __restrict__ o1, ushort* __restrict__ o2,
                 const int* __restrict__ edst, int* __restrict__ deg,
                 int* __restrict__ order, int nconv4, int E)
{
    int tid = blockIdx.x * blockDim.x + threadIdx.x;
    if (tid < nconv4) {                  // x f32 -> bf16, 4 elems/thread
        int i = tid << 2;
        float4 v = *(const float4*)(x + i);
        ushort4 o;
        o.x = f2bf(v.x); o.y = f2bf(v.y); o.z = f2bf(v.z); o.w = f2bf(v.w);
        *(ushort4*)(xbf + i) = o;
        return;
    }
    int t = tid - nconv4;
    if (t < 16 * 4 * 64) { prefrag_one(W1, o1, t, 4, 256); return; }
    t -= 16 * 4 * 64;
    if (t < 4 * 8 * 64)  { prefrag_one(W2, o2, t, 8, 64); return; }
    t -= 4 * 8 * 64;
    int i = t << 2;                      // degree histogram, 4 edges/thread
    if (i + 3 < E) {
        int4 v = *(const int4*)(edst + i);
        int4 o;
        o.x = atomicAdd(&deg[v.x], 1);
        o.y = atomicAdd(&deg[v.y], 1);
        o.z = atomicAdd(&deg[v.z], 1);
        o.w = atomicAdd(&deg[v.w], 1);
        *(int4*)(order + i) = o;
    } else {
        for (; i < E; ++i) order[i] = atomicAdd(&deg[edst[i]], 1);
    }
}

// ---------------- single-block exclusive scan (2 barriers) -----------------
__global__ __launch_bounds__(1024)
void scan_rowptr(const int* __restrict__ deg, int* __restrict__ rowptr, int N)
{
    __shared__ int wsums[16];
    const int tid = threadIdx.x, lane = tid & 63, wid = tid >> 6;
    const int N4 = N >> 2;              // int4 count (N % 4 == 0)
    const int b4 = tid * 13;            // 13 int4 = 52 elems per thread
    int tsum = 0;
    #pragma unroll
    for (int k = 0; k < 13; ++k) {
        int i4 = b4 + k;
        if (i4 < N4) {
            int4 v = ((const int4*)deg)[i4];
            tsum += (v.x + v.y) + (v.z + v.w);
        }
    }
    int sc = tsum;                      // inclusive wave scan
    #pragma unroll
    for (int off = 1; off < 64; off <<= 1) {
        int t = __shfl_up(sc, off);
        if (lane >= off) sc += t;
    }
    if (lane == 63) wsums[wid] = sc;
    __syncthreads();
    if (wid == 0) {
        int wv = (lane < 16) ? wsums[lane] : 0;
        #pragma unroll
        for (int off = 1; off < 16; off <<= 1) {
            int t = __shfl_up(wv, off);
            if (lane >= off) wv += t;
        }
        if (lane < 16) wsums[lane] = wv;
    }
    __syncthreads();
    int run = (wid ? wsums[wid - 1] : 0) + sc - tsum;   // exclusive start
    #pragma unroll
    for (int k = 0; k < 13; ++k) {
        int i4 = b4 + k;
        if (i4 < N4) {
            int4 v = ((const int4*)deg)[i4];
            int4 o;
            o.x = run; o.y = run + v.x; o.z = o.y + v.y; o.w = o.z + v.z;
            ((int4*)rowptr)[i4] = o;
            run += (v.x + v.y) + (v.z + v.w);
        }
    }
    if (tid == 1023) rowptr[N] = run;   // all data precedes thread 1023
}

// ---------------- MFMA GEMM body (device fn) -------------------------------
template<int J, int T, int H>
__device__ inline void gemm_body(int wid, const ushort* __restrict__ A,
                                 const ushort* __restrict__ Bf,
                                 ushort* __restrict__ Cbf,
                                 const float* __restrict__ attS,
                                 const float* __restrict__ attD,
                                 float* __restrict__ as_,
                                 float* __restrict__ ad_, int M)
{
    constexpr int K = 32 * T;
    constexpr int NN = 16 * J;
    const int l = threadIdx.x & 63;
    const int base = wid * 16;
    if (base >= M) return;
    const int lm = l & 15, lg = l >> 4;

    short8 a[T];
    const ushort* ap = A + (size_t)(base + lm) * K + lg * 8;
    #pragma unroll
    for (int t = 0; t < T; ++t) a[t] = *(const short8*)(ap + t * 32);

    f32x4 acc[J];
    #pragma unroll
    for (int j = 0; j < J; ++j) acc[j] = (f32x4){0.f, 0.f, 0.f, 0.f};

    const ushort* bp = Bf + (size_t)l * 8;
    #pragma unroll
    for (int j = 0; j < J; ++j)
        #pragma unroll
        for (int t = 0; t < T; ++t) {
            short8 b = *(const short8*)(bp + (size_t)(j * T + t) * 512);
            acc[j] = __builtin_amdgcn_mfma_f32_16x16x32_bf16(a[t], b, acc[j], 0, 0, 0);
        }

    float sp[H][4], dp[H][4];
    #pragma unroll
    for (int h = 0; h < H; ++h)
        #pragma unroll
        for (int r = 0; r < 4; ++r) { sp[h][r] = 0.f; dp[h][r] = 0.f; }

    #pragma unroll
    for (int j = 0; j < J; ++j) {
        const int h = j / (J / H);
        const int coff = (j % (J / H)) * 16 + lm;
        float ws = attS[h * 64 + coff];
        float wd = attD[h * 64 + coff];
        #pragma unroll
        for (int r = 0; r < 4; ++r) {
            int row = base + lg * 4 + r;
            Cbf[(size_t)row * NN + j * 16 + lm] = f2bf(acc[j][r]);
            sp[h][r] = fmaf(acc[j][r], ws, sp[h][r]);
            dp[h][r] = fmaf(acc[j][r], wd, dp[h][r]);
        }
    }
    #pragma unroll
    for (int h = 0; h < H; ++h)
        #pragma unroll
        for (int r = 0; r < 4; ++r) {
            float s = sp[h][r], d = dp[h][r];
            s += __shfl_xor(s, 1); d += __shfl_xor(d, 1);
            s += __shfl_xor(s, 2); d += __shfl_xor(d, 2);
            s += __shfl_xor(s, 4); d += __shfl_xor(d, 4);
            s += __shfl_xor(s, 8); d += __shfl_xor(d, 8);
            if (lm == 0) {
                int row = base + lg * 4 + r;
                as_[row * H + h] = s;
                ad_[row * H + h] = d;
            }
        }
}

// ---- K3: gemm1 + atomic-free scatter in one launch ------------------------
__global__ __launch_bounds__(256)
void scatter_gemm1(const ushort* __restrict__ A, const ushort* __restrict__ Bf,
                   ushort* __restrict__ Cbf, const float* __restrict__ attS,
                   const float* __restrict__ attD, float* __restrict__ as_,
                   float* __restrict__ ad_, int M, int gemmBlocks,
                   const int* __restrict__ esrc, const int* __restrict__ edst,
                   const int* __restrict__ rowptr, const int* __restrict__ order,
                   int* __restrict__ csr_src, int E)
{
    if ((int)blockIdx.x < gemmBlocks) {
        int wid = blockIdx.x * (blockDim.x >> 6) + (threadIdx.x >> 6);
        gemm_body<16, 4, 4>(wid, A, Bf, Cbf, attS, attD, as_, ad_, M);
        return;
    }
    // scatter: pure streaming placement, no atomics in the critical path
    int i = (blockIdx.x - gemmBlocks) * blockDim.x + threadIdx.x;
    if (i >= E) return;
    csr_src[rowptr[edst[i]] + order[i]] = esrc[i];
}

// ---------------- gemm2 (standalone) ---------------------------------------
template<int J, int T, int H>
__global__ __launch_bounds__(256)
void gemm_mfma(const ushort* __restrict__ A, const ushort* __restrict__ Bf,
               ushort* __restrict__ Cbf, const float* __restrict__ attS,
               const float* __restrict__ attD, float* __restrict__ as_,
               float* __restrict__ ad_, int M)
{
    int wid = blockIdx.x * (blockDim.x >> 6) + (threadIdx.x >> 6);
    gemm_body<J, T, H>(wid, A, Bf, Cbf, attS, attD, as_, ad_, M);
}

// -------- layer-1 aggregation (R12 form): 4x unroll; shfl p-dedup ----------
__global__ __launch_bounds__(256)
void aggregate_l1(const int* __restrict__ rowptr, const int* __restrict__ csr_src,
                  const ushort* __restrict__ h1, const float* __restrict__ as_,
                  const float* __restrict__ ad_, const float* __restrict__ bias,
                  ushort* __restrict__ outbf, int N)
{
    int w = (blockIdx.x * blockDim.x + threadIdx.x) >> 6;
    int lane = threadIdx.x & 63;
    if (w >= N) return;
    const int head = lane >> 4;          // 4 heads x 16 lanes
    const int c0 = lane << 2;            // ushort4 per lane
    const int my = lane & 3;             // this lane's coef slot
    const int hb = lane & 48;            // head-group base lane
    const float ad = ad_[w * 4 + head];
    float4 acc;
    float dsum;

    {   // implicit self-loop
        float el = as_[w * 4 + head] + ad;
        el = el > 0.f ? el : LRELU_SLOPE * el;
        float p = __expf(el);
        ushort4 u = *(const ushort4*)(h1 + (size_t)w * 256 + c0);
        acc.x = p * bf2f(u.x); acc.y = p * bf2f(u.y);
        acc.z = p * bf2f(u.z); acc.w = p * bf2f(u.w);
        dsum = p;
    }

    int e = rowptr[w];
    const int e1 = rowptr[w + 1];
    for (; e + 3 < e1; e += 4) {         // 4 independent gathers in flight
        int s0 = csr_src[e],     s1 = csr_src[e + 1];
        int s2 = csr_src[e + 2], s3 = csr_src[e + 3];
        ushort4 u0 = *(const ushort4*)(h1 + (size_t)s0 * 256 + c0);
        ushort4 u1 = *(const ushort4*)(h1 + (size_t)s1 * 256 + c0);
        ushort4 u2 = *(const ushort4*)(h1 + (size_t)s2 * 256 + c0);
        ushort4 u3 = *(const ushort4*)(h1 + (size_t)s3 * 256 + c0);
        int ms = s0;
        ms = (my == 1) ? s1 : ms;
        ms = (my == 2) ? s2 : ms;
        ms = (my == 3) ? s3 : ms;
        float ev = as_[ms * 4 + head] + ad;
        ev = ev > 0.f ? ev : LRELU_SLOPE * ev;
        float pl = __expf(ev);
        float p0 = __shfl(pl, hb | 0);
        float p1 = __shfl(pl, hb | 1);
        float p2 = __shfl(pl, hb | 2);
        float p3 = __shfl(pl, hb | 3);
        acc.x = fmaf(p0, bf2f(u0.x), acc.x); acc.y = fmaf(p0, bf2f(u0.y), acc.y);
        acc.z = fmaf(p0, bf2f(u0.z), acc.z); acc.w = fmaf(p0, bf2f(u0.w), acc.w);
        acc.x = fmaf(p1, bf2f(u1.x), acc.x); acc.y = fmaf(p1, bf2f(u1.y), acc.y);
        acc.z = fmaf(p1, bf2f(u1.z), acc.z); acc.w = fmaf(p1, bf2f(u1.w), acc.w);
        acc.x = fmaf(p2, bf2f(u2.x), acc.x); acc.y = fmaf(p2, bf2f(u2.y), acc.y);
        acc.z = fmaf(p2, bf2f(u2.z), acc.z); acc.w = fmaf(p2, bf2f(u2.w), acc.w);
        acc.x = fmaf(p3, bf2f(u3.x), acc.x); acc.y = fmaf(p3, bf2f(u3.y), acc.y);
        acc.z = fmaf(p3, bf2f(u3.z), acc.z); acc.w = fmaf(p3, bf2f(u3.w), acc.w);
        dsum += (p0 + p1) + (p2 + p3);
    }
    for (; e < e1; ++e) {
        int s0 = csr_src[e];
        float e0 = as_[s0 * 4 + head] + ad;
        e0 = e0 > 0.f ? e0 : LRELU_SLOPE * e0;
        float p0 = __expf(e0);
        ushort4 u0 = *(const ushort4*)(h1 + (size_t)s0 * 256 + c0);
        acc.x = fmaf(p0, bf2f(u0.x), acc.x); acc.y = fmaf(p0, bf2f(u0.y), acc.y);
        acc.z = fmaf(p0, bf2f(u0.z), acc.z); acc.w = fmaf(p0, bf2f(u0.w), acc.w);
        dsum += p0;
    }
    const float inv = 1.f / (dsum + 1e-16f);
    const float4 b = *(const float4*)(bias + c0);
    float ox = acc.x * inv + b.x; ox = ox > 0.f ? ox : expm1f(ox);
    float oy = acc.y * inv + b.y; oy = oy > 0.f ? oy : expm1f(oy);
    float oz = acc.z * inv + b.z; oz = oz > 0.f ? oz : expm1f(oz);
    float ow = acc.w * inv + b.w; ow = ow > 0.f ? ow : expm1f(ow);
    ushort4 o;
    o.x = f2bf(ox); o.y = f2bf(oy); o.z = f2bf(oz); o.w = f2bf(ow);
    *(ushort4*)(outbf + (size_t)w * 256 + c0) = o;
}

// -------- layer-2 aggregation + scoring head (R12 form) --------------------
__global__ __launch_bounds__(256)
void aggregate_l2(const int* __restrict__ rowptr, const int* __restrict__ csr_src,
                  const ushort* __restrict__ h2, const float* __restrict__ as_,
                  const float* __restrict__ ad_, const float* __restrict__ b2,
                  const float* __restrict__ Wsv, const float* __restrict__ bs,
                  float* __restrict__ hout, float* __restrict__ scores, int N)
{
    int w = (blockIdx.x * blockDim.x + threadIdx.x) >> 6;
    int lane = threadIdx.x & 63;
    if (w >= N) return;
    const int my = lane & 3;
    const float ad = ad_[w];
    float acc, dsum;
    {   // implicit self-loop
        float el = as_[w] + ad;
        el = el > 0.f ? el : LRELU_SLOPE * el;
        float p = __expf(el);
        acc = p * bf2f(h2[(size_t)w * 64 + lane]);
        dsum = p;
    }
    int e = rowptr[w];
    const int e1 = rowptr[w + 1];
    for (; e + 3 < e1; e += 4) {
        int s0 = csr_src[e],     s1 = csr_src[e + 1];
        int s2 = csr_src[e + 2], s3 = csr_src[e + 3];
        ushort f0 = h2[(size_t)s0 * 64 + lane];
        ushort f1 = h2[(size_t)s1 * 64 + lane];
        ushort f2 = h2[(size_t)s2 * 64 + lane];
        ushort f3 = h2[(size_t)s3 * 64 + lane];
        int ms = s0;
        ms = (my == 1) ? s1 : ms;
        ms = (my == 2) ? s2 : ms;
        ms = (my == 3) ? s3 : ms;
        float ev = as_[ms] + ad;
        ev = ev > 0.f ? ev : LRELU_SLOPE * ev;
        float pl = __expf(ev);
        float p0 = __shfl(pl, 0);
        float p1 = __shfl(pl, 1);
        float p2 = __shfl(pl, 2);
        float p3 = __shfl(pl, 3);
        acc = fmaf(p0, bf2f(f0), acc);
        acc = fmaf(p1, bf2f(f1), acc);
        acc = fmaf(p2, bf2f(f2), acc);
        acc = fmaf(p3, bf2f(f3), acc);
        dsum += (p0 + p1) + (p2 + p3);
    }
    for (; e < e1; ++e) {
        int s0 = csr_src[e];
        float e0 = as_[s0] + ad;
        e0 = e0 > 0.f ? e0 : LRELU_SLOPE * e0;
        float p0 = __expf(e0);
        acc = fmaf(p0, bf2f(h2[(size_t)s0 * 64 + lane]), acc);
        dsum += p0;
    }
    float v = acc / (dsum + 1e-16f) + b2[lane];
    v = v > 0.f ? v : expm1f(v);
    hout[(size_t)w * 64 + lane] = v;
    float sc = v * Wsv[lane];
    #pragma unroll
    for (int off = 32; off; off >>= 1) sc += __shfl_down(sc, off);
    if (lane == 0) scores[w] = sc + bs[0];
}

// ---------------------------------------------------------------------------
extern "C" void kernel_launch(void* const* d_in, const int* in_sizes, int n_in,
                              void* d_out, int out_size, void* d_ws, size_t ws_size,
                              hipStream_t stream)
{
    const float* x    = (const float*)d_in[0];
    const int*   ei   = (const int*)d_in[1];
    const float* W1   = (const float*)d_in[2];
    const float* as1w = (const float*)d_in[3];
    const float* ad1w = (const float*)d_in[4];
    const float* b1   = (const float*)d_in[5];
    const float* W2   = (const float*)d_in[6];
    const float* as2w = (const float*)d_in[7];
    const float* ad2w = (const float*)d_in[8];
    const float* b2   = (const float*)d_in[9];
    const float* Ws   = (const float*)d_in[10];
    const float* bs   = (const float*)d_in[11];

    const int N  = in_sizes[0] / 128;   // 50000
    const int E  = in_sizes[1] / 2;     // 800000
    const int* esrc = ei;
    const int* edst = ei + E;

    // ---- workspace layout (16B-aligned chunks) ----
    ushort* h1bf  = (ushort*)d_ws;                       // N*256 bf16
    ushort* hl1bf = h1bf + (size_t)N * 256;              // N*256 bf16
    ushort* h2bf  = hl1bf + (size_t)N * 256;             // N*64 bf16
    ushort* xbf   = h2bf + (size_t)N * 64;               // N*128 bf16
    ushort* bfr1  = xbf + (size_t)N * 128;               // 32768
    ushort* bfr2  = bfr1 + 32768;                        // 16384
    float*  as1   = (float*)(bfr2 + 16384);              // N*4
    float*  ad1   = as1 + (size_t)N * 4;                 // N*4
    float*  as2   = ad1 + (size_t)N * 4;                 // N
    float*  ad2   = as2 + N;                             // N
    int*    deg    = (int*)(ad2 + N);                    // N
    int*    order  = deg + N;                            // E
    int*    rowptr = order + E;                          // N+1 (+pad)
    int*    csr_src= rowptr + N + 4;                     // E

    float* hout   = (float*)d_out;                       // N*64
    float* scores = hout + (size_t)N * 64;               // N

    // ---------------- K0: zero deg ----------------
    hipMemsetAsync(deg, 0, (size_t)N * sizeof(int), stream);

    // ---------------- K1: hist(+order) + conv + prefrags ----------------
    const int nconv4 = N * 128 / 4;                      // 1,600,000
    const int nfrag  = 16 * 4 * 64 + 4 * 8 * 64;         // 6,144
    const int nhist  = (E + 3) / 4;                      // 200,000
    fused_front<<<(nconv4 + nfrag + nhist + 255) / 256, 256, 0, stream>>>(
        x, xbf, W1, W2, bfr1, bfr2, edst, deg, order, nconv4, E);

    // ---------------- K2: rowptr scan ----------------
    scan_rowptr<<<1, 1024, 0, stream>>>(deg, rowptr, N);

    // ---------------- K3: gemm1 + atomic-free scatter ----------------
    const int gemmBlocks    = (N / 16 + 3) / 4;          // 782
    const int scatterBlocks = (E + 255) / 256;           // 3125
    scatter_gemm1<<<gemmBlocks + scatterBlocks, 256, 0, stream>>>(
        xbf, bfr1, h1bf, as1w, ad1w, as1, ad1, N, gemmBlocks,
        esrc, edst, rowptr, order, csr_src, E);

    // ---------------- K4: agg1 ----------------
    aggregate_l1<<<((size_t)N * 64 + 255) / 256, 256, 0, stream>>>(
        rowptr, csr_src, h1bf, as1, ad1, b1, hl1bf, N);

    // ---------------- K5: gemm2 ----------------
    gemm_mfma<4, 8, 1><<<(N / 16 + 3) / 4, 256, 0, stream>>>(
        hl1bf, bfr2, h2bf, as2w, ad2w, as2, ad2, N);

    // ---------------- K6: agg2 + scoring head ----------------
    aggregate_l2<<<((size_t)N * 64 + 255) / 256, 256, 0, stream>>>(
        rowptr, csr_src, h2bf, as2, ad2, b2, Ws, bs, hout, scores, N);
}

// Round 20
// 221.696 us; speedup vs baseline: 3.2059x; 1.0215x over previous
//
#include <hip/hip_runtime.h>
#include <hip/hip_bf16.h>
#include <math.h>

// ---------------------------------------------------------------------------
// DualHeadGAT R20 = R16 (best, 226.5us) + R14's agg1+gemm2 fusion:
//  - atomic-free scatter (order captured in K1's histogram).
//  - K3: full-wave gemm1 co-launched with streaming scatter (R16 form).
//  - agg1+gemm2 fused: block owns 16 nodes; hl1 tile lives in LDS only
//    (kills the gemm2 dispatch+gap and the 25.6MB hl1 round-trip). R14
//    verified numerics; its total regression was the K3 quarter-wave
//    change, not this fusion (75.9us vs agg1 67 + gemm2 10 + gap 7).
//  - 6 dispatches: memset, fused_front, scan, gemm1+scatter, agg1_gemm2,
//    agg2.
// N=50000, IN=128, E=800000. f32 in/out, int32 edges.
// ---------------------------------------------------------------------------

#define LRELU_SLOPE 0.2f

typedef __attribute__((ext_vector_type(8))) short short8;   // 8 bf16 = 4 VGPR
typedef __attribute__((ext_vector_type(4))) float f32x4;

__device__ inline ushort f2bf(float f) {            // RNE f32 -> bf16
    uint u = __float_as_uint(f);
    return (ushort)((u + 0x7FFFu + ((u >> 16) & 1u)) >> 16);
}
__device__ inline float bf2f(ushort u) {
    return __uint_as_float(((uint)u) << 16);
}

// ------- pre-fragment W[K][16J] (f32, row-major) into MFMA B-frag order ----
__device__ inline void prefrag_one(const float* __restrict__ W,
                                   ushort* __restrict__ out,
                                   int tid, int T, int ldn)
{
    int l = tid & 63, jt = tid >> 6;
    int t = jt % T, j = jt / T;
    int n = j * 16 + (l & 15);
    int k0 = t * 32 + (l >> 4) * 8;
    ushort o[8];
    #pragma unroll
    for (int b = 0; b < 8; ++b) o[b] = f2bf(W[(size_t)(k0 + b) * ldn + n]);
    *(short8*)(out + (size_t)tid * 8) = *(short8*)o;
}

// ---- K1: degree hist (captures order) + x conversion + weight prefrags ----
__global__ __launch_bounds__(256)
void fused_front(const float* __restrict__ x, ushort* __restrict__ xbf,
                 const float* __restrict__ W1, const float* __restrict__ W2,
                 ushort* __restrict__ o1, ushort* __restrict__ o2,
                 const int* __restrict__ edst, int* __restrict__ deg,
                 int* __restrict__ order, int nconv4, int E)
{
    int tid = blockIdx.x * blockDim.x + threadIdx.x;
    if (tid < nconv4) {                  // x f32 -> bf16, 4 elems/thread
        int i = tid << 2;
        float4 v = *(const float4*)(x + i);
        ushort4 o;
        o.x = f2bf(v.x); o.y = f2bf(v.y); o.z = f2bf(v.z); o.w = f2bf(v.w);
        *(ushort4*)(xbf + i) = o;
        return;
    }
    int t = tid - nconv4;
    if (t < 16 * 4 * 64) { prefrag_one(W1, o1, t, 4, 256); return; }
    t -= 16 * 4 * 64;
    if (t < 4 * 8 * 64)  { prefrag_one(W2, o2, t, 8, 64); return; }
    t -= 4 * 8 * 64;
    int i = t << 2;                      // degree histogram, 4 edges/thread
    if (i + 3 < E) {
        int4 v = *(const int4*)(edst + i);
        int4 o;
        o.x = atomicAdd(&deg[v.x], 1);
        o.y = atomicAdd(&deg[v.y], 1);
        o.z = atomicAdd(&deg[v.z], 1);
        o.w = atomicAdd(&deg[v.w], 1);
        *(int4*)(order + i) = o;
    } else {
        for (; i < E; ++i) order[i] = atomicAdd(&deg[edst[i]], 1);
    }
}

// ---------------- single-block exclusive scan (2 barriers) -----------------
__global__ __launch_bounds__(1024)
void scan_rowptr(const int* __restrict__ deg, int* __restrict__ rowptr, int N)
{
    __shared__ int wsums[16];
    const int tid = threadIdx.x, lane = tid & 63, wid = tid >> 6;
    const int N4 = N >> 2;              // int4 count (N % 4 == 0)
    const int b4 = tid * 13;            // 13 int4 = 52 elems per thread
    int tsum = 0;
    #pragma unroll
    for (int k = 0; k < 13; ++k) {
        int i4 = b4 + k;
        if (i4 < N4) {
            int4 v = ((const int4*)deg)[i4];
            tsum += (v.x + v.y) + (v.z + v.w);
        }
    }
    int sc = tsum;                      // inclusive wave scan
    #pragma unroll
    for (int off = 1; off < 64; off <<= 1) {
        int t = __shfl_up(sc, off);
        if (lane >= off) sc += t;
    }
    if (lane == 63) wsums[wid] = sc;
    __syncthreads();
    if (wid == 0) {
        int wv = (lane < 16) ? wsums[lane] : 0;
        #pragma unroll
        for (int off = 1; off < 16; off <<= 1) {
            int t = __shfl_up(wv, off);
            if (lane >= off) wv += t;
        }
        if (lane < 16) wsums[lane] = wv;
    }
    __syncthreads();
    int run = (wid ? wsums[wid - 1] : 0) + sc - tsum;   // exclusive start
    #pragma unroll
    for (int k = 0; k < 13; ++k) {
        int i4 = b4 + k;
        if (i4 < N4) {
            int4 v = ((const int4*)deg)[i4];
            int4 o;
            o.x = run; o.y = run + v.x; o.z = o.y + v.y; o.w = o.z + v.z;
            ((int4*)rowptr)[i4] = o;
            run += (v.x + v.y) + (v.z + v.w);
        }
    }
    if (tid == 1023) rowptr[N] = run;   // all data precedes thread 1023
}

// ---------------- MFMA GEMM body (device fn, K3's gemm1) -------------------
template<int J, int T, int H>
__device__ inline void gemm_body(int wid, const ushort* __restrict__ A,
                                 const ushort* __restrict__ Bf,
                                 ushort* __restrict__ Cbf,
                                 const float* __restrict__ attS,
                                 const float* __restrict__ attD,
                                 float* __restrict__ as_,
                                 float* __restrict__ ad_, int M)
{
    constexpr int K = 32 * T;
    constexpr int NN = 16 * J;
    const int l = threadIdx.x & 63;
    const int base = wid * 16;
    if (base >= M) return;
    const int lm = l & 15, lg = l >> 4;

    short8 a[T];
    const ushort* ap = A + (size_t)(base + lm) * K + lg * 8;
    #pragma unroll
    for (int t = 0; t < T; ++t) a[t] = *(const short8*)(ap + t * 32);

    f32x4 acc[J];
    #pragma unroll
    for (int j = 0; j < J; ++j) acc[j] = (f32x4){0.f, 0.f, 0.f, 0.f};

    const ushort* bp = Bf + (size_t)l * 8;
    #pragma unroll
    for (int j = 0; j < J; ++j)
        #pragma unroll
        for (int t = 0; t < T; ++t) {
            short8 b = *(const short8*)(bp + (size_t)(j * T + t) * 512);
            acc[j] = __builtin_amdgcn_mfma_f32_16x16x32_bf16(a[t], b, acc[j], 0, 0, 0);
        }

    float sp[H][4], dp[H][4];
    #pragma unroll
    for (int h = 0; h < H; ++h)
        #pragma unroll
        for (int r = 0; r < 4; ++r) { sp[h][r] = 0.f; dp[h][r] = 0.f; }

    #pragma unroll
    for (int j = 0; j < J; ++j) {
        const int h = j / (J / H);
        const int coff = (j % (J / H)) * 16 + lm;
        float ws = attS[h * 64 + coff];
        float wd = attD[h * 64 + coff];
        #pragma unroll
        for (int r = 0; r < 4; ++r) {
            int row = base + lg * 4 + r;
            Cbf[(size_t)row * NN + j * 16 + lm] = f2bf(acc[j][r]);
            sp[h][r] = fmaf(acc[j][r], ws, sp[h][r]);
            dp[h][r] = fmaf(acc[j][r], wd, dp[h][r]);
        }
    }
    #pragma unroll
    for (int h = 0; h < H; ++h)
        #pragma unroll
        for (int r = 0; r < 4; ++r) {
            float s = sp[h][r], d = dp[h][r];
            s += __shfl_xor(s, 1); d += __shfl_xor(d, 1);
            s += __shfl_xor(s, 2); d += __shfl_xor(d, 2);
            s += __shfl_xor(s, 4); d += __shfl_xor(d, 4);
            s += __shfl_xor(s, 8); d += __shfl_xor(d, 8);
            if (lm == 0) {
                int row = base + lg * 4 + r;
                as_[row * H + h] = s;
                ad_[row * H + h] = d;
            }
        }
}

// ---- K3: gemm1 + atomic-free scatter in one launch ------------------------
__global__ __launch_bounds__(256)
void scatter_gemm1(const ushort* __restrict__ A, const ushort* __restrict__ Bf,
                   ushort* __restrict__ Cbf, const float* __restrict__ attS,
                   const float* __restrict__ attD, float* __restrict__ as_,
                   float* __restrict__ ad_, int M, int gemmBlocks,
                   const int* __restrict__ esrc, const int* __restrict__ edst,
                   const int* __restrict__ rowptr, const int* __restrict__ order,
                   int* __restrict__ csr_src, int E)
{
    if ((int)blockIdx.x < gemmBlocks) {
        int wid = blockIdx.x * (blockDim.x >> 6) + (threadIdx.x >> 6);
        gemm_body<16, 4, 4>(wid, A, Bf, Cbf, attS, attD, as_, ad_, M);
        return;
    }
    // scatter: pure streaming placement, no atomics in the critical path
    int i = (blockIdx.x - gemmBlocks) * blockDim.x + threadIdx.x;
    if (i >= E) return;
    csr_src[rowptr[edst[i]] + order[i]] = esrc[i];
}

// ---- K4: agg1 (16 nodes/block, hl1 in LDS) + gemm2 fused (R14 form) -------
__global__ __launch_bounds__(256)
void agg1_gemm2(const int* __restrict__ rowptr, const int* __restrict__ csr_src,
                const ushort* __restrict__ h1, const float* __restrict__ as_,
                const float* __restrict__ ad_, const float* __restrict__ bias,
                const ushort* __restrict__ Bf2, const float* __restrict__ attS2,
                const float* __restrict__ attD2, float* __restrict__ as2,
                float* __restrict__ ad2, ushort* __restrict__ h2bf, int N)
{
    __shared__ ushort hl[16][264];       // 16 node rows, +8 pad
    __shared__ float partS[4][16], partD[4][16];
    const int lane = threadIdx.x & 63;
    const int v = threadIdx.x >> 6;      // wave 0..3
    const int nbase = blockIdx.x * 16;
    const int head = lane >> 4;
    const int c0 = lane << 2;
    const int my = lane & 3;
    const int hb = lane & 48;

    // ---------- phase 1: agg1 for 4 nodes per wave (R12 math) ----------
    for (int qn = 0; qn < 4; ++qn) {
        const int w = nbase + v * 4 + qn;
        if (w >= N) break;
        const float ad = ad_[w * 4 + head];
        float4 acc;
        float dsum;
        {   // implicit self-loop
            float el = as_[w * 4 + head] + ad;
            el = el > 0.f ? el : LRELU_SLOPE * el;
            float p = __expf(el);
            ushort4 u = *(const ushort4*)(h1 + (size_t)w * 256 + c0);
            acc.x = p * bf2f(u.x); acc.y = p * bf2f(u.y);
            acc.z = p * bf2f(u.z); acc.w = p * bf2f(u.w);
            dsum = p;
        }
        int e = rowptr[w];
        const int e1 = rowptr[w + 1];
        for (; e + 3 < e1; e += 4) {
            int s0 = csr_src[e],     s1 = csr_src[e + 1];
            int s2 = csr_src[e + 2], s3 = csr_src[e + 3];
            ushort4 u0 = *(const ushort4*)(h1 + (size_t)s0 * 256 + c0);
            ushort4 u1 = *(const ushort4*)(h1 + (size_t)s1 * 256 + c0);
            ushort4 u2 = *(const ushort4*)(h1 + (size_t)s2 * 256 + c0);
            ushort4 u3 = *(const ushort4*)(h1 + (size_t)s3 * 256 + c0);
            int ms = s0;
            ms = (my == 1) ? s1 : ms;
            ms = (my == 2) ? s2 : ms;
            ms = (my == 3) ? s3 : ms;
            float ev = as_[ms * 4 + head] + ad;
            ev = ev > 0.f ? ev : LRELU_SLOPE * ev;
            float pl = __expf(ev);
            float p0 = __shfl(pl, hb | 0);
            float p1 = __shfl(pl, hb | 1);
            float p2 = __shfl(pl, hb | 2);
            float p3 = __shfl(pl, hb | 3);
            acc.x = fmaf(p0, bf2f(u0.x), acc.x); acc.y = fmaf(p0, bf2f(u0.y), acc.y);
            acc.z = fmaf(p0, bf2f(u0.z), acc.z); acc.w = fmaf(p0, bf2f(u0.w), acc.w);
            acc.x = fmaf(p1, bf2f(u1.x), acc.x); acc.y = fmaf(p1, bf2f(u1.y), acc.y);
            acc.z = fmaf(p1, bf2f(u1.z), acc.z); acc.w = fmaf(p1, bf2f(u1.w), acc.w);
            acc.x = fmaf(p2, bf2f(u2.x), acc.x); acc.y = fmaf(p2, bf2f(u2.y), acc.y);
            acc.z = fmaf(p2, bf2f(u2.z), acc.z); acc.w = fmaf(p2, bf2f(u2.w), acc.w);
            acc.x = fmaf(p3, bf2f(u3.x), acc.x); acc.y = fmaf(p3, bf2f(u3.y), acc.y);
            acc.z = fmaf(p3, bf2f(u3.z), acc.z); acc.w = fmaf(p3, bf2f(u3.w), acc.w);
            dsum += (p0 + p1) + (p2 + p3);
        }
        for (; e < e1; ++e) {
            int s0 = csr_src[e];
            float e0 = as_[s0 * 4 + head] + ad;
            e0 = e0 > 0.f ? e0 : LRELU_SLOPE * e0;
            float p0 = __expf(e0);
            ushort4 u0 = *(const ushort4*)(h1 + (size_t)s0 * 256 + c0);
            acc.x = fmaf(p0, bf2f(u0.x), acc.x); acc.y = fmaf(p0, bf2f(u0.y), acc.y);
            acc.z = fmaf(p0, bf2f(u0.z), acc.z); acc.w = fmaf(p0, bf2f(u0.w), acc.w);
            dsum += p0;
        }
        const float inv = 1.f / (dsum + 1e-16f);
        const float4 b = *(const float4*)(bias + c0);
        float ox = acc.x * inv + b.x; ox = ox > 0.f ? ox : expm1f(ox);
        float oy = acc.y * inv + b.y; oy = oy > 0.f ? oy : expm1f(oy);
        float oz = acc.z * inv + b.z; oz = oz > 0.f ? oz : expm1f(oz);
        float ow = acc.w * inv + b.w; ow = ow > 0.f ? ow : expm1f(ow);
        ushort4 o;
        o.x = f2bf(ox); o.y = f2bf(oy); o.z = f2bf(oz); o.w = f2bf(ow);
        *(ushort4*)&hl[v * 4 + qn][c0] = o;
    }
    __syncthreads();

    // ---------- phase 2: gemm2 (16 rows x 64 cols, quarter per wave) ----
    {
        const int lm = lane & 15, lg = lane >> 4;
        short8 a[8];
        #pragma unroll
        for (int t = 0; t < 8; ++t)
            a[t] = *(const short8*)&hl[lm][lg * 8 + t * 32];
        f32x4 acc = (f32x4){0.f, 0.f, 0.f, 0.f};
        const ushort* bp = Bf2 + (size_t)(v * 8) * 512 + (size_t)lane * 8;
        #pragma unroll
        for (int t = 0; t < 8; ++t) {
            short8 b = *(const short8*)(bp + (size_t)t * 512);
            acc = __builtin_amdgcn_mfma_f32_16x16x32_bf16(a[t], b, acc, 0, 0, 0);
        }
        const float ws = attS2[v * 16 + lm];
        const float wd = attD2[v * 16 + lm];
        float sp[4], dp[4];
        #pragma unroll
        for (int r = 0; r < 4; ++r) {
            int row = nbase + lg * 4 + r;
            if (row < N)
                h2bf[(size_t)row * 64 + v * 16 + lm] = f2bf(acc[r]);
            sp[r] = acc[r] * ws;
            dp[r] = acc[r] * wd;
        }
        #pragma unroll
        for (int r = 0; r < 4; ++r) {
            float s = sp[r], d = dp[r];
            s += __shfl_xor(s, 1); d += __shfl_xor(d, 1);
            s += __shfl_xor(s, 2); d += __shfl_xor(d, 2);
            s += __shfl_xor(s, 4); d += __shfl_xor(d, 4);
            s += __shfl_xor(s, 8); d += __shfl_xor(d, 8);
            if (lm == 0) {
                partS[v][lg * 4 + r] = s;
                partD[v][lg * 4 + r] = d;
            }
        }
    }
    __syncthreads();
    if (threadIdx.x < 16) {
        int row = nbase + threadIdx.x;
        if (row < N) {
            int t = threadIdx.x;
            as2[row] = ((partS[0][t] + partS[1][t]) + (partS[2][t] + partS[3][t]));
            ad2[row] = ((partD[0][t] + partD[1][t]) + (partD[2][t] + partD[3][t]));
        }
    }
}

// -------- layer-2 aggregation + scoring head (R12 form) --------------------
__global__ __launch_bounds__(256)
void aggregate_l2(const int* __restrict__ rowptr, const int* __restrict__ csr_src,
                  const ushort* __restrict__ h2, const float* __restrict__ as_,
                  const float* __restrict__ ad_, const float* __restrict__ b2,
                  const float* __restrict__ Wsv, const float* __restrict__ bs,
                  float* __restrict__ hout, float* __restrict__ scores, int N)
{
    int w = (blockIdx.x * blockDim.x + threadIdx.x) >> 6;
    int lane = threadIdx.x & 63;
    if (w >= N) return;
    const int my = lane & 3;
    const float ad = ad_[w];
    float acc, dsum;
    {   // implicit self-loop
        float el = as_[w] + ad;
        el = el > 0.f ? el : LRELU_SLOPE * el;
        float p = __expf(el);
        acc = p * bf2f(h2[(size_t)w * 64 + lane]);
        dsum = p;
    }
    int e = rowptr[w];
    const int e1 = rowptr[w + 1];
    for (; e + 3 < e1; e += 4) {
        int s0 = csr_src[e],     s1 = csr_src[e + 1];
        int s2 = csr_src[e + 2], s3 = csr_src[e + 3];
        ushort f0 = h2[(size_t)s0 * 64 + lane];
        ushort f1 = h2[(size_t)s1 * 64 + lane];
        ushort f2 = h2[(size_t)s2 * 64 + lane];
        ushort f3 = h2[(size_t)s3 * 64 + lane];
        int ms = s0;
        ms = (my == 1) ? s1 : ms;
        ms = (my == 2) ? s2 : ms;
        ms = (my == 3) ? s3 : ms;
        float ev = as_[ms] + ad;
        ev = ev > 0.f ? ev : LRELU_SLOPE * ev;
        float pl = __expf(ev);
        float p0 = __shfl(pl, 0);
        float p1 = __shfl(pl, 1);
        float p2 = __shfl(pl, 2);
        float p3 = __shfl(pl, 3);
        acc = fmaf(p0, bf2f(f0), acc);
        acc = fmaf(p1, bf2f(f1), acc);
        acc = fmaf(p2, bf2f(f2), acc);
        acc = fmaf(p3, bf2f(f3), acc);
        dsum += (p0 + p1) + (p2 + p3);
    }
    for (; e < e1; ++e) {
        int s0 = csr_src[e];
        float e0 = as_[s0] + ad;
        e0 = e0 > 0.f ? e0 : LRELU_SLOPE * e0;
        float p0 = __expf(e0);
        acc = fmaf(p0, bf2f(h2[(size_t)s0 * 64 + lane]), acc);
        dsum += p0;
    }
    float v = acc / (dsum + 1e-16f) + b2[lane];
    v = v > 0.f ? v : expm1f(v);
    hout[(size_t)w * 64 + lane] = v;
    float sc = v * Wsv[lane];
    #pragma unroll
    for (int off = 32; off; off >>= 1) sc += __shfl_down(sc, off);
    if (lane == 0) scores[w] = sc + bs[0];
}

// ---------------------------------------------------------------------------
extern "C" void kernel_launch(void* const* d_in, const int* in_sizes, int n_in,
                              void* d_out, int out_size, void* d_ws, size_t ws_size,
                              hipStream_t stream)
{
    const float* x    = (const float*)d_in[0];
    const int*   ei   = (const int*)d_in[1];
    const float* W1   = (const float*)d_in[2];
    const float* as1w = (const float*)d_in[3];
    const float* ad1w = (const float*)d_in[4];
    const float* b1   = (const float*)d_in[5];
    const float* W2   = (const float*)d_in[6];
    const float* as2w = (const float*)d_in[7];
    const float* ad2w = (const float*)d_in[8];
    const float* b2   = (const float*)d_in[9];
    const float* Ws   = (const float*)d_in[10];
    const float* bs   = (const float*)d_in[11];

    const int N  = in_sizes[0] / 128;   // 50000
    const int E  = in_sizes[1] / 2;     // 800000
    const int* esrc = ei;
    const int* edst = ei + E;

    // ---- workspace layout (16B-aligned chunks) ----
    ushort* h1bf  = (ushort*)d_ws;                       // N*256 bf16
    ushort* h2bf  = h1bf + (size_t)N * 256;              // N*64 bf16
    ushort* xbf   = h2bf + (size_t)N * 64;               // N*128 bf16
    ushort* bfr1  = xbf + (size_t)N * 128;               // 32768
    ushort* bfr2  = bfr1 + 32768;                        // 16384
    float*  as1   = (float*)(bfr2 + 16384);              // N*4
    float*  ad1   = as1 + (size_t)N * 4;                 // N*4
    float*  as2   = ad1 + (size_t)N * 4;                 // N
    float*  ad2   = as2 + N;                             // N
    int*    deg    = (int*)(ad2 + N);                    // N
    int*    order  = deg + N;                            // E
    int*    rowptr = order + E;                          // N+1 (+pad)
    int*    csr_src= rowptr + N + 4;                     // E

    float* hout   = (float*)d_out;                       // N*64
    float* scores = hout + (size_t)N * 64;               // N

    // ---------------- K0: zero deg ----------------
    hipMemsetAsync(deg, 0, (size_t)N * sizeof(int), stream);

    // ---------------- K1: hist(+order) + conv + prefrags ----------------
    const int nconv4 = N * 128 / 4;                      // 1,600,000
    const int nfrag  = 16 * 4 * 64 + 4 * 8 * 64;         // 6,144
    const int nhist  = (E + 3) / 4;                      // 200,000
    fused_front<<<(nconv4 + nfrag + nhist + 255) / 256, 256, 0, stream>>>(
        x, xbf, W1, W2, bfr1, bfr2, edst, deg, order, nconv4, E);

    // ---------------- K2: rowptr scan ----------------
    scan_rowptr<<<1, 1024, 0, stream>>>(deg, rowptr, N);

    // ---------------- K3: gemm1 + atomic-free scatter ----------------
    const int gemmBlocks    = (N / 16 + 3) / 4;          // 782
    const int scatterBlocks = (E + 255) / 256;           // 3125
    scatter_gemm1<<<gemmBlocks + scatterBlocks, 256, 0, stream>>>(
        xbf, bfr1, h1bf, as1w, ad1w, as1, ad1, N, gemmBlocks,
        esrc, edst, rowptr, order, csr_src, E);

    // ---------------- K4: agg1 + gemm2 fused ----------------
    agg1_gemm2<<<(N + 15) / 16, 256, 0, stream>>>(
        rowptr, csr_src, h1bf, as1, ad1, b1,
        bfr2, as2w, ad2w, as2, ad2, h2bf, N);

    // ---------------- K5: agg2 + scoring head ----------------
    aggregate_l2<<<((size_t)N * 64 + 255) / 256, 256, 0, stream>>>(
        rowptr, csr_src, h2bf, as2, ad2, b2, Ws, bs, hout, scores, N);
}